// Round 14
// baseline (100.163 us; speedup 1.0000x reference)
//
#include <hip/hip_runtime.h>
#include <math.h>

#define OUT_H 7
#define OUT_W 7
#define NBINS 49
#define RFL(x) __builtin_amdgcn_readfirstlane(x)

// R13 post-mortem: binder is per-VMEM-inst/line cost (~35 wave-loads x ~10cyc
// x 128 waves/CU ~ 19us), not VALU/bytes. v14: dwordx4 batch loads (lane =
// 4 row-slots x 16 col-quads -> one load = 4-row slab, 35 -> ~9 insts/wave)
// + col-quad clamping to the roi window (uniform bounds, dup quads load
// identical data - benign under max; lines 140 -> ~93, L2 bytes 293 -> 165MB).
// Cross-row merge via 1KB wave-private LDS slab (write x4, read 4 rows at
// col=lane, conflict-free, same-wave ordering -> no barriers). Phase 2 is
// R13's validated code (absmax 0 since R4). Cols outside the window are
// stale in LDS/racc but phase-2 bin x-ranges are inside the window.
// Bin bounds: exact integer floor(k*roi/7) == (k*roi)/7.
// Grid bx = n*64+cg: XCD = cg%8 -> fixed 2MB channel subset per XCD L2.
__global__ __launch_bounds__(256) void roipool_v14(
    const float* __restrict__ feat, const int* __restrict__ rois,
    float* __restrict__ out)
{
    constexpr int C = 256, H = 64, W = 64, HW = H * W;
    __shared__ float scratch[4][4][64];        // [wave][row-slot][col], 4KB
    __shared__ float racc_lds[4][OUT_H][65];   // [wave][ph][x], 7.3KB

    const int bx   = blockIdx.x;
    const int n    = bx >> 6;              // roi (128)
    const int cg   = bx & 63;              // channel group
    const int tid  = threadIdx.x;
    const int lane = tid & 63;
    const int wave = RFL(tid >> 6);
    const int c    = cg * 4 + wave;        // scalar

    const int* r = rois + n * 5;
    const int b  = RFL(r[0]);
    const int x1 = RFL(r[1]);
    const int y1 = RFL(r[2]);
    const int roi_w = RFL(r[3]) - x1 + 1;  // scalar
    const int roi_h = RFL(r[4]) - y1 + 1;  // scalar

    const float* plane = feat + (size_t)(b * C + c) * HW;   // scalar base

    // Batch-layout decode: row-slot rs = lane>>4 (0..3), col-quad q = lane&15
    // clamped to the window's quad range (computed ONCE; dups load identical
    // global data -> benign under max, and cut lines touched ~1.6x).
    const int rs  = lane >> 4;
    const int qlo = RFL(x1 >> 2);
    const int qhi = RFL((x1 + roi_w - 1) >> 2);
    int q = lane & 15;
    q = q < qlo ? qlo : q;
    q = q > qhi ? qhi : q;
    const int coloff = q * 4;              // element offset in row, 16B-aligned

    int hb[OUT_H + 1];                     // scalar bin bounds
#pragma unroll
    for (int k = 0; k <= OUT_H; ++k) hb[k] = RFL((k * roi_h) / OUT_H);

    // ---- Batch 1: rows yb..yb+3 (clamped to bin last row) as ONE x4 load
    // per ph; all 7 loads issued before any use -> single vmcnt exposure.
    float4 v1[OUT_H];
#pragma unroll
    for (int ph = 0; ph < OUT_H; ++ph) {
        const int yb = y1 + hb[ph];
        int yl = y1 + hb[ph + 1] - 1;      // last row of bin (scalar)
        yl = yl > yb ? yl : yb;            // empty-bin guard
        int row = yb + rs;
        row = row < yl ? row : yl;         // per-lane row clamp (dup ok)
        v1[ph] = *(const float4*)(plane + row * W + coloff);
    }

    float racc[OUT_H];
#pragma unroll
    for (int ph = 0; ph < OUT_H; ++ph) {
        // stage slab -> merge 4 rows column-wise (lane = x); wave-private,
        // same-wave LDS ordering makes the slot reuse across ph safe.
        *(float4*)&scratch[wave][rs][coloff] = v1[ph];
        const float a0 = scratch[wave][0][lane];
        const float a1 = scratch[wave][1][lane];
        const float a2 = scratch[wave][2][lane];
        const float a3 = scratch[wave][3][lane];
        racc[ph] = fmaxf(fmaxf(a0, a1), fmaxf(a2, a3));
    }

    // ---- Tall bins (h>4; h <= ceil(48/7)=7): rows yb+4..yb+6, one more x4.
    if (roi_h > 28) {                      // scalar: only then any bin h>4
        float4 v2[OUT_H];
#pragma unroll
        for (int ph = 0; ph < OUT_H; ++ph) {
            if (hb[ph + 1] - hb[ph] > 4) {             // scalar
                const int yb = y1 + hb[ph];
                const int yl = y1 + hb[ph + 1] - 1;
                int row = yb + 4 + rs;
                row = row < yl ? row : yl;             // dup rows, same bin
                v2[ph] = *(const float4*)(plane + row * W + coloff);
            }
        }
#pragma unroll
        for (int ph = 0; ph < OUT_H; ++ph) {
            if (hb[ph + 1] - hb[ph] > 4) {
                *(float4*)&scratch[wave][rs][coloff] = v2[ph];
                const float a0 = scratch[wave][0][lane];
                const float a1 = scratch[wave][1][lane];
                const float a2 = scratch[wave][2][lane];
                const float a3 = scratch[wave][3][lane];
                racc[ph] = fmaxf(racc[ph],
                                 fmaxf(fmaxf(a0, a1), fmaxf(a2, a3)));
            }
        }
    }

    // ---- Phase 2 (identical to validated R13) ----
#pragma unroll
    for (int ph = 0; ph < OUT_H; ++ph) racc_lds[wave][ph][lane] = racc[ph];

    if (lane < NBINS) {
        const int ph = lane / OUT_W;
        const int pw = lane - ph * OUT_W;

        const int hsL = (ph * roi_h) / OUT_H;
        const int heL = ((ph + 1) * roi_h) / OUT_H;
        const int ws  = (pw * roi_w) / OUT_W;
        const int we  = ((pw + 1) * roi_w) / OUT_W;

        const int xs = x1 + ws;
        int xl = x1 + we - 1;
        xl = xl > xs ? xl : xs;            // empty-bin guard

        float g[8];                        // max bin width 7 <= 8
#pragma unroll
        for (int j = 0; j < 8; ++j) {
            int x = xs + j;
            x = x < xl ? x : xl;           // clamp: duplicates harmless
            g[j] = racc_lds[wave][ph][x];
        }
        float m = fmaxf(fmaxf(fmaxf(g[0], g[1]), fmaxf(g[2], g[3])),
                        fmaxf(fmaxf(g[4], g[5]), fmaxf(g[6], g[7])));

        const bool valid = (heL > hsL) && (we > ws);
        out[(size_t)(n * C + c) * NBINS + lane] = valid ? m : 0.0f;
    }
}

extern "C" void kernel_launch(void* const* d_in, const int* in_sizes, int n_in,
                              void* d_out, int out_size, void* d_ws, size_t ws_size,
                              hipStream_t stream) {
    const float* feat = (const float*)d_in[0];
    const int*   rois = (const int*)d_in[1];
    float*       out  = (float*)d_out;

    const int N = in_sizes[1] / 5;     // 128 rois
    const int n_blocks = N * 64;       // 4 waves/block, 1 wave per (n,c)

    roipool_v14<<<n_blocks, 256, 0, stream>>>(feat, rois, out);
}